// Round 1
// baseline (7517.389 us; speedup 1.0000x reference)
//
#include <hip/hip_runtime.h>

#define IMG 784       // 28*28
#define H1HW 676      // 26*26
#define H1SZ 21632    // 32*676
#define POOLSZ 9216   // 64*12*12
#define FC1N 128
#define K2OCG 16
#define KC 32

// ---------------- conv1 + relu: x[B,1,28,28] -> h1[B,32,26,26] ----------------
__global__ __launch_bounds__(256) void k1_conv1(const float* __restrict__ x,
    const float* __restrict__ w1, const float* __restrict__ b1,
    float* __restrict__ h1) {
  int img = blockIdx.x;
  __shared__ float xs[IMG];
  __shared__ float ws[288];
  __shared__ float bs[32];
  const float* xp = x + (size_t)img * IMG;
  for (int i = threadIdx.x; i < IMG; i += 256) xs[i] = xp[i];
  for (int i = threadIdx.x; i < 288; i += 256) ws[i] = w1[i];
  if (threadIdx.x < 32) bs[threadIdx.x] = b1[threadIdx.x];
  __syncthreads();
  float* hp = h1 + (size_t)img * H1SZ;
  for (int o = threadIdx.x; o < H1SZ; o += 256) {
    int oc = o / H1HW;
    int pos = o - oc * H1HW;
    int oy = pos / 26;
    int ox = pos - oy * 26;
    float s = bs[oc];
    const float* wp = ws + oc * 9;
    const float* xr = xs + oy * 28 + ox;
    #pragma unroll
    for (int ky = 0; ky < 3; ++ky)
      #pragma unroll
      for (int kx = 0; kx < 3; ++kx)
        s = fmaf(xr[ky * 28 + kx], wp[ky * 3 + kx], s);
    hp[o] = fmaxf(s, 0.f);
  }
}

// ------- conv2 + relu + maxpool2x2: h1[B,32,26,26] -> pooled[B,64*12*12] -------
// grid (nimg, 4): blockIdx.y selects a group of 16 output channels.
// thread t: ocl = t>>4 (local out channel), ts = t&15; owns 9 pooled positions.
__global__ __launch_bounds__(256) void k2_conv2pool(const float* __restrict__ h1,
    const float* __restrict__ w2, const float* __restrict__ b2,
    float* __restrict__ pooled) {
  int img = blockIdx.x;
  int oc0 = blockIdx.y * K2OCG;
  __shared__ float hs[8][H1HW];          // 21632 B
  __shared__ float wsh[K2OCG][8][9];     //  4608 B
  int t = threadIdx.x;
  int ocl = t >> 4;
  int ts = t & 15;
  float acc[9][4];
  #pragma unroll
  for (int k = 0; k < 9; ++k) {
    acc[k][0] = 0.f; acc[k][1] = 0.f; acc[k][2] = 0.f; acc[k][3] = 0.f;
  }
  const float* hp = h1 + (size_t)img * H1SZ;
  float* hsf = &hs[0][0];
  for (int ic0 = 0; ic0 < 32; ic0 += 8) {
    __syncthreads();
    for (int i = t; i < 8 * H1HW; i += 256) hsf[i] = hp[ic0 * H1HW + i];
    for (int i = t; i < K2OCG * 72; i += 256) {
      int o = i / 72;
      int r = i - o * 72;
      int ic = r / 9;
      int tap = r - ic * 9;
      wsh[o][ic][tap] = w2[(size_t)(oc0 + o) * 288 + (ic0 + ic) * 9 + tap];
    }
    __syncthreads();
    #pragma unroll
    for (int ic = 0; ic < 8; ++ic) {
      float w[9];
      #pragma unroll
      for (int q = 0; q < 9; ++q) w[q] = wsh[ocl][ic][q];
      #pragma unroll
      for (int k = 0; k < 9; ++k) {
        int sp = ts + 16 * k;         // 0..143
        int py = sp / 12;
        int px = sp - py * 12;
        const float* base = &hs[ic][2 * py * 26 + 2 * px];
        float xv[4][4];
        #pragma unroll
        for (int r = 0; r < 4; ++r)
          #pragma unroll
          for (int c = 0; c < 4; ++c)
            xv[r][c] = base[r * 26 + c];
        #pragma unroll
        for (int dy = 0; dy < 2; ++dy)
          #pragma unroll
          for (int dx = 0; dx < 2; ++dx) {
            float s = acc[k][dy * 2 + dx];
            #pragma unroll
            for (int ky = 0; ky < 3; ++ky)
              #pragma unroll
              for (int kx = 0; kx < 3; ++kx)
                s = fmaf(xv[dy + ky][dx + kx], w[ky * 3 + kx], s);
            acc[k][dy * 2 + dx] = s;
          }
      }
    }
  }
  float bias = b2[oc0 + ocl];
  float* pp = pooled + (size_t)img * POOLSZ + (size_t)(oc0 + ocl) * 144;
  #pragma unroll
  for (int k = 0; k < 9; ++k) {
    int sp = ts + 16 * k;
    float m = fmaxf(fmaxf(acc[k][0], acc[k][1]), fmaxf(acc[k][2], acc[k][3]));
    pp[sp] = fmaxf(m + bias, 0.f);
  }
}

// ---------------- fc1 + relu: pooled[nr,9216] @ fc1_w[128,9216]^T ----------------
// block: 32 rows x 128 cols, 256 threads, thread = 4x4 microtile.
__global__ __launch_bounds__(256) void k3_fc1(const float* __restrict__ a,
    const float* __restrict__ w, const float* __restrict__ bias,
    float* __restrict__ out, int nr) {
  __shared__ float at[KC][36];    // [kk][row], pad 36 for conflict-free/aligned f4
  __shared__ float wt[KC][132];   // [kk][col], pad 132
  int row0 = blockIdx.x * 32;
  int t = threadIdx.x;
  int tr = t & 7;        // row group 0..7 -> rows tr*4..tr*4+3
  int tc = t >> 3;       // col group 0..31 -> cols tc*4..tc*4+3
  float acc[4][4];
  #pragma unroll
  for (int i = 0; i < 4; ++i)
    #pragma unroll
    for (int j = 0; j < 4; ++j) acc[i][j] = 0.f;

  for (int k0 = 0; k0 < 9216; k0 += KC) {
    __syncthreads();
    // stage A tile (32 rows x KC), transposed into at[kk][r]
    for (int idx = t; idx < 32 * KC; idx += 256) {
      int kk = idx & 31;
      int r = idx >> 5;
      int row = row0 + r;
      at[kk][r] = (row < nr) ? a[(size_t)row * 9216 + k0 + kk] : 0.f;
    }
    // stage W tile (128 cols x KC), transposed into wt[kk][c]
    for (int idx = t; idx < 128 * KC; idx += 256) {
      int kk = idx & 31;
      int c = idx >> 5;
      wt[kk][c] = w[(size_t)c * 9216 + k0 + kk];
    }
    __syncthreads();
    #pragma unroll
    for (int kk = 0; kk < KC; ++kk) {
      float4 a4 = *(const float4*)&at[kk][tr * 4];
      float4 b4 = *(const float4*)&wt[kk][tc * 4];
      float av[4] = {a4.x, a4.y, a4.z, a4.w};
      float bv[4] = {b4.x, b4.y, b4.z, b4.w};
      #pragma unroll
      for (int i = 0; i < 4; ++i)
        #pragma unroll
        for (int j = 0; j < 4; ++j)
          acc[i][j] = fmaf(av[i], bv[j], acc[i][j]);
    }
  }
  #pragma unroll
  for (int i = 0; i < 4; ++i) {
    int r = row0 + tr * 4 + i;
    if (r < nr) {
      #pragma unroll
      for (int j = 0; j < 4; ++j) {
        int c = tc * 4 + j;
        out[(size_t)r * FC1N + c] = fmaxf(acc[i][j] + bias[c], 0.f);
      }
    }
  }
}

// ---------------- fc2: h[nr,128] @ fc2_w[10,128]^T -> out[nr,10] ----------------
__global__ __launch_bounds__(256) void k4_fc2(const float* __restrict__ h,
    const float* __restrict__ w, const float* __restrict__ bias,
    float* __restrict__ out, int nr) {
  int idx = blockIdx.x * 256 + threadIdx.x;
  if (idx >= nr * 10) return;
  int b = idx / 10;
  int j = idx - b * 10;
  const float4* hp = (const float4*)(h + (size_t)b * 128);
  const float4* wp = (const float4*)(w + (size_t)j * 128);
  float s = 0.f;
  #pragma unroll
  for (int q = 0; q < 32; ++q) {
    float4 hv = hp[q];
    float4 wv = wp[q];
    s = fmaf(hv.x, wv.x, s);
    s = fmaf(hv.y, wv.y, s);
    s = fmaf(hv.z, wv.z, s);
    s = fmaf(hv.w, wv.w, s);
  }
  out[idx] = s + bias[j];
}

extern "C" void kernel_launch(void* const* d_in, const int* in_sizes, int n_in,
                              void* d_out, int out_size, void* d_ws, size_t ws_size,
                              hipStream_t stream) {
  const float* x   = (const float*)d_in[0];
  const float* w1  = (const float*)d_in[1];
  const float* b1  = (const float*)d_in[2];
  const float* w2  = (const float*)d_in[3];
  const float* b2  = (const float*)d_in[4];
  const float* fw1 = (const float*)d_in[5];
  const float* fb1 = (const float*)d_in[6];
  const float* fw2 = (const float*)d_in[7];
  const float* fb2 = (const float*)d_in[8];
  float* out = (float*)d_out;

  const int B = 4096;
  const size_t per_img_bytes = (size_t)(H1SZ + POOLSZ + FC1N) * sizeof(float);
  int Bc = (int)(ws_size / per_img_bytes);
  if (Bc > B) Bc = B;
  if (Bc < 1) Bc = 1;

  float* h1     = (float*)d_ws;
  float* pooled = h1 + (size_t)Bc * H1SZ;
  float* f1o    = pooled + (size_t)Bc * POOLSZ;

  for (int i0 = 0; i0 < B; i0 += Bc) {
    int nr = (B - i0 < Bc) ? (B - i0) : Bc;
    k1_conv1<<<nr, 256, 0, stream>>>(x + (size_t)i0 * IMG, w1, b1, h1);
    k2_conv2pool<<<dim3(nr, 4), 256, 0, stream>>>(h1, w2, b2, pooled);
    k3_fc1<<<(nr + 31) / 32, 256, 0, stream>>>(pooled, fw1, fb1, f1o, nr);
    k4_fc2<<<(nr * 10 + 255) / 256, 256, 0, stream>>>(f1o, fw2, fb2,
                                                      out + (size_t)i0 * 10, nr);
  }
}

// Round 2
// 2916.585 us; speedup vs baseline: 2.5775x; 2.5775x over previous
//
#include <hip/hip_runtime.h>

using short8 = __attribute__((ext_vector_type(8))) short;
using f32x4  = __attribute__((ext_vector_type(4))) float;

#define H1_STRIDE 55296      // bytes per image (54 chunks of 1024)
#define H1_BYTES  54080      // 26*26*40*2
#define WT_ELEMS  23040      // 9*64*40
#define WT_BYTES  46080
#define POOLSZ    9216       // 144*64
#define FC1N      128
#define KC        32

#define GLL16(gp, lp) __builtin_amdgcn_global_load_lds( \
    (const __attribute__((address_space(1))) void*)(gp), \
    (__attribute__((address_space(3))) void*)(lp), 16, 0, 0)

static __device__ __forceinline__ unsigned short f2bf(float f) {
  unsigned int u = __builtin_bit_cast(unsigned int, f);
  unsigned int r = (u + 0x7FFFu + ((u >> 16) & 1u)) >> 16;
  return (unsigned short)r;
}

// ---- conv1 + relu -> h1 bf16 HWC [img][26*26][40] (ch 32..39 pad, unread) ----
__global__ __launch_bounds__(256) void k1_conv1(const float* __restrict__ x,
    const float* __restrict__ w1, const float* __restrict__ b1,
    unsigned short* __restrict__ h1) {
  int img = blockIdx.x;
  __shared__ float xs[784];
  __shared__ float ws1[288];
  __shared__ float bs[32];
  __shared__ unsigned short h1s[27040];   // 54080 B
  int t = threadIdx.x;
  const float* xp = x + (size_t)img * 784;
  for (int i = t; i < 784; i += 256) xs[i] = xp[i];
  for (int i = t; i < 288; i += 256) ws1[i] = w1[i];
  if (t < 32) bs[t] = b1[t];
  __syncthreads();
  for (int pos = t; pos < 676; pos += 256) {
    int oy = pos / 26, ox = pos - oy * 26;
    float xv[9];
    #pragma unroll
    for (int ky = 0; ky < 3; ++ky)
      #pragma unroll
      for (int kx = 0; kx < 3; ++kx)
        xv[ky * 3 + kx] = xs[(oy + ky) * 28 + ox + kx];
    unsigned short* hr = &h1s[pos * 40];
    #pragma unroll
    for (int oc = 0; oc < 32; ++oc) {
      float s = bs[oc];
      #pragma unroll
      for (int q = 0; q < 9; ++q) s = fmaf(xv[q], ws1[oc * 9 + q], s);
      hr[oc] = f2bf(fmaxf(s, 0.f));
    }
  }
  __syncthreads();
  const uint4* srcv = (const uint4*)h1s;
  uint4* dstv = (uint4*)((char*)h1 + (size_t)img * H1_STRIDE);
  for (int i = t; i < H1_BYTES / 16; i += 256) dstv[i] = srcv[i];
}

// ---- one-off: w2 fp32 [64][32][9] -> wt bf16 [9][64][40] (ic-minor, padded) ----
__global__ __launch_bounds__(256) void k_wt(const float* __restrict__ w2,
    unsigned short* __restrict__ wt) {
  int idx = blockIdx.x * 256 + threadIdx.x;
  if (idx >= WT_ELEMS) return;
  int tap = idx / 2560;
  int r = idx - tap * 2560;
  int oc = r / 40;
  int ic = r - oc * 40;
  unsigned short v = 0;
  if (ic < 32) v = f2bf(w2[oc * 288 + ic * 9 + tap]);
  wt[idx] = v;
}

// ---- one-off: fc1_w [128][9216 (oc*144+sp)] -> fw1t [128][9216 (sp*64+oc)] ----
__global__ __launch_bounds__(256) void k_fw1t(const float* __restrict__ w,
    float* __restrict__ wt) {
  int c = blockIdx.x;
  __shared__ float row[9216];
  int t = threadIdx.x;
  const float* src = w + (size_t)c * 9216;
  for (int i = t; i < 9216; i += 256) row[i] = src[i];
  __syncthreads();
  float* dst = wt + (size_t)c * 9216;
  for (int k = t; k < 9216; k += 256) {
    int sp = k >> 6, oc = k & 63;
    dst[k] = row[oc * 144 + sp];
  }
}

// ---- conv2 + relu + maxpool via MFMA: h1 HWC bf16 -> pooled fp32 HWC [img][144][64]
// One block per image, 4 waves. Wave owns 9 M-tiles (16 positions each).
// M-tile mt: pr = mt/3 (pooled row), tc = mt%3; tile row i -> (y=2pr+(i&1), x=8tc+(i>>1)).
// A frag (lane l): row=l&15, k(ic)=(l>>4)*8+j  -> one ds_read_b128 from hs.
// B frag (lane l): col(oc)=l&15, k(ic)=(l>>4)*8+j -> one ds_read_b128 from wsh.
// C regs r=0..3 of lane = the 2x2 pool window of pooled (pr, 4*tc + (l>>4)).
__global__ __launch_bounds__(256) void k2_mfma(const unsigned short* __restrict__ h1,
    const unsigned short* __restrict__ wt, const float* __restrict__ b2,
    float* __restrict__ pooled) {
  int img = blockIdx.x;
  __shared__ unsigned short hs[27648];    // 55296 B
  __shared__ unsigned short wsh[23040];   // 46080 B
  int t = threadIdx.x;
  int wv = t >> 6, ln = t & 63;
  const char* gs = (const char*)h1 + (size_t)img * H1_STRIDE + ln * 16;
  char* hsb = (char*)hs;
  #pragma unroll
  for (int c = 0; c < 14; ++c) {          // 54 chunks of 1024 B
    int cc = wv + c * 4;
    if (cc < 54) GLL16(gs + cc * 1024, hsb + cc * 1024);
  }
  const char* gw = (const char*)wt + ln * 16;
  char* wsb = (char*)wsh;
  #pragma unroll
  for (int c = 0; c < 12; ++c) {          // 45 chunks of 1024 B
    int cc = wv + c * 4;
    if (cc < 45) GLL16(gw + cc * 1024, wsb + cc * 1024);
  }
  __syncthreads();

  int col = t & 15;
  int g = (t >> 4) & 3;
  int wave = t >> 6;

  int abase[9];
  #pragma unroll
  for (int m = 0; m < 9; ++m) {
    int mt = wave * 9 + m;
    int pr = mt / 3, tc = mt - pr * 3;
    int y = 2 * pr + (col & 1);
    int xx = 8 * tc + (col >> 1);
    abase[m] = (y * 26 + xx) * 80 + g * 16;
  }
  int bbase = col * 80 + g * 16;

  f32x4 acc[9][4];
  #pragma unroll
  for (int m = 0; m < 9; ++m)
    #pragma unroll
    for (int n = 0; n < 4; ++n)
      acc[m][n] = (f32x4){0.f, 0.f, 0.f, 0.f};

  #pragma unroll
  for (int tap = 0; tap < 9; ++tap) {
    int ky = tap / 3, kx = tap - ky * 3;
    int toff = (ky * 26 + kx) * 80;
    short8 bf[4];
    #pragma unroll
    for (int n = 0; n < 4; ++n)
      bf[n] = *(const short8*)(wsb + bbase + (tap * 64 + n * 16) * 80);
    #pragma unroll
    for (int m = 0; m < 9; ++m) {
      short8 af = *(const short8*)(hsb + abase[m] + toff);
      #pragma unroll
      for (int n = 0; n < 4; ++n)
        acc[m][n] = __builtin_amdgcn_mfma_f32_16x16x32_bf16(af, bf[n], acc[m][n], 0, 0, 0);
    }
  }

  float bias[4];
  #pragma unroll
  for (int n = 0; n < 4; ++n) bias[n] = b2[n * 16 + col];
  float* pp = pooled + (size_t)img * POOLSZ;
  #pragma unroll
  for (int m = 0; m < 9; ++m) {
    int mt = wave * 9 + m;
    int pr = mt / 3, tc = mt - pr * 3;
    int sp = pr * 12 + tc * 4 + g;
    #pragma unroll
    for (int n = 0; n < 4; ++n) {
      f32x4 a = acc[m][n];
      float v = fmaxf(fmaxf(a[0], a[1]), fmaxf(a[2], a[3]));
      pp[sp * 64 + n * 16 + col] = fmaxf(v + bias[n], 0.f);
    }
  }
}

// ---- fc1 + relu: pooled[nr,9216] @ fw1t[128,9216]^T (K in sp*64+oc order) ----
__global__ __launch_bounds__(256) void k3_fc1(const float* __restrict__ a,
    const float* __restrict__ w, const float* __restrict__ bias,
    float* __restrict__ out, int nr) {
  __shared__ float at[KC][36];
  __shared__ float wtile[KC][132];
  int row0 = blockIdx.x * 32;
  int t = threadIdx.x;
  int tr = t & 7;
  int tc = t >> 3;
  float acc[4][4];
  #pragma unroll
  for (int i = 0; i < 4; ++i)
    #pragma unroll
    for (int j = 0; j < 4; ++j) acc[i][j] = 0.f;

  for (int k0 = 0; k0 < 9216; k0 += KC) {
    __syncthreads();
    for (int idx = t; idx < 32 * KC; idx += 256) {
      int kk = idx & 31;
      int r = idx >> 5;
      int row = row0 + r;
      at[kk][r] = (row < nr) ? a[(size_t)row * 9216 + k0 + kk] : 0.f;
    }
    for (int idx = t; idx < 128 * KC; idx += 256) {
      int kk = idx & 31;
      int c = idx >> 5;
      wtile[kk][c] = w[(size_t)c * 9216 + k0 + kk];
    }
    __syncthreads();
    #pragma unroll
    for (int kk = 0; kk < KC; ++kk) {
      float4 a4 = *(const float4*)&at[kk][tr * 4];
      float4 b4 = *(const float4*)&wtile[kk][tc * 4];
      float av[4] = {a4.x, a4.y, a4.z, a4.w};
      float bv[4] = {b4.x, b4.y, b4.z, b4.w};
      #pragma unroll
      for (int i = 0; i < 4; ++i)
        #pragma unroll
        for (int j = 0; j < 4; ++j)
          acc[i][j] = fmaf(av[i], bv[j], acc[i][j]);
    }
  }
  #pragma unroll
  for (int i = 0; i < 4; ++i) {
    int r = row0 + tr * 4 + i;
    if (r < nr) {
      #pragma unroll
      for (int j = 0; j < 4; ++j) {
        int c = tc * 4 + j;
        out[(size_t)r * FC1N + c] = fmaxf(acc[i][j] + bias[c], 0.f);
      }
    }
  }
}

// ---- fc2 ----
__global__ __launch_bounds__(256) void k4_fc2(const float* __restrict__ h,
    const float* __restrict__ w, const float* __restrict__ bias,
    float* __restrict__ out, int nr) {
  int idx = blockIdx.x * 256 + threadIdx.x;
  if (idx >= nr * 10) return;
  int b = idx / 10;
  int j = idx - b * 10;
  const float4* hp = (const float4*)(h + (size_t)b * 128);
  const float4* wp = (const float4*)(w + (size_t)j * 128);
  float s = 0.f;
  #pragma unroll
  for (int q = 0; q < 32; ++q) {
    float4 hv = hp[q];
    float4 wv = wp[q];
    s = fmaf(hv.x, wv.x, s);
    s = fmaf(hv.y, wv.y, s);
    s = fmaf(hv.z, wv.z, s);
    s = fmaf(hv.w, wv.w, s);
  }
  out[idx] = s + bias[j];
}

extern "C" void kernel_launch(void* const* d_in, const int* in_sizes, int n_in,
                              void* d_out, int out_size, void* d_ws, size_t ws_size,
                              hipStream_t stream) {
  const float* x   = (const float*)d_in[0];
  const float* w1  = (const float*)d_in[1];
  const float* b1  = (const float*)d_in[2];
  const float* w2  = (const float*)d_in[3];
  const float* b2  = (const float*)d_in[4];
  const float* fw1 = (const float*)d_in[5];
  const float* fb1 = (const float*)d_in[6];
  const float* fw2 = (const float*)d_in[7];
  const float* fb2 = (const float*)d_in[8];
  float* out = (float*)d_out;

  const int B = in_sizes[0] / 784;

  unsigned short* wt = (unsigned short*)d_ws;                     // 46080 B
  float* fw1t = (float*)((char*)d_ws + WT_BYTES);                 // 4718592 B
  const size_t carve = WT_BYTES + (size_t)9216 * 128 * 4;
  char* base = (char*)d_ws + carve;
  size_t avail = (ws_size > carve) ? ws_size - carve : 0;
  const size_t per_img = H1_STRIDE + (size_t)POOLSZ * 4 + (size_t)FC1N * 4;  // 92672
  int Bc = (int)(avail / per_img);
  if (Bc > B) Bc = B;
  if (Bc < 1) Bc = 1;

  unsigned short* h1 = (unsigned short*)base;
  float* pooled = (float*)(base + (size_t)Bc * H1_STRIDE);
  float* f1o = pooled + (size_t)Bc * POOLSZ;

  k_wt<<<(WT_ELEMS + 255) / 256, 256, 0, stream>>>(w2, wt);
  k_fw1t<<<128, 256, 0, stream>>>(fw1, fw1t);

  for (int i0 = 0; i0 < B; i0 += Bc) {
    int nr = (B - i0 < Bc) ? (B - i0) : Bc;
    k1_conv1<<<nr, 256, 0, stream>>>(x + (size_t)i0 * 784, w1, b1, h1);
    k2_mfma<<<nr, 256, 0, stream>>>(h1, wt, b2, pooled);
    k3_fc1<<<(nr + 31) / 32, 256, 0, stream>>>(pooled, fw1t, fb1, f1o, nr);
    k4_fc2<<<(nr * 10 + 255) / 256, 256, 0, stream>>>(f1o, fw2, fb2,
                                                      out + (size_t)i0 * 10, nr);
  }
}

// Round 3
// 337.700 us; speedup vs baseline: 22.2606x; 8.6366x over previous
//
#include <hip/hip_runtime.h>

using short8 = __attribute__((ext_vector_type(8))) short;
using f32x4  = __attribute__((ext_vector_type(4))) float;

#define H1_STRIDE 55296      // bytes per image (54 chunks of 1024)
#define H1_BYTES  54080      // 26*26*40*2
#define WT_ELEMS  23040      // 9*64*40
#define WT_BYTES  46080
#define POOLN     9216       // 144*64 elements (bf16)
#define FC1N      128

#define GLL16(gp, lp) __builtin_amdgcn_global_load_lds( \
    (const __attribute__((address_space(1))) void*)(gp), \
    (__attribute__((address_space(3))) void*)(lp), 16, 0, 0)

static __device__ __forceinline__ unsigned short f2bf(float f) {
  unsigned int u = __builtin_bit_cast(unsigned int, f);
  unsigned int r = (u + 0x7FFFu + ((u >> 16) & 1u)) >> 16;
  return (unsigned short)r;
}

// ---- conv1 + relu -> h1 bf16 HWC [img][26*26][40] (ch 32..39 pad, unread) ----
__global__ __launch_bounds__(256) void k1_conv1(const float* __restrict__ x,
    const float* __restrict__ w1, const float* __restrict__ b1,
    unsigned short* __restrict__ h1) {
  int img = blockIdx.x;
  __shared__ float xs[784];
  __shared__ float ws1[288];
  __shared__ float bs[32];
  __shared__ __align__(16) unsigned short h1s[27040];   // 54080 B
  int t = threadIdx.x;
  const float* xp = x + (size_t)img * 784;
  for (int i = t; i < 784; i += 256) xs[i] = xp[i];
  for (int i = t; i < 288; i += 256) ws1[i] = w1[i];
  if (t < 32) bs[t] = b1[t];
  __syncthreads();
  for (int pos = t; pos < 676; pos += 256) {
    int oy = pos / 26, ox = pos - oy * 26;
    float xv[9];
    #pragma unroll
    for (int ky = 0; ky < 3; ++ky)
      #pragma unroll
      for (int kx = 0; kx < 3; ++kx)
        xv[ky * 3 + kx] = xs[(oy + ky) * 28 + ox + kx];
    unsigned short* hr = &h1s[pos * 40];
    #pragma unroll
    for (int oc = 0; oc < 32; ++oc) {
      float s = bs[oc];
      #pragma unroll
      for (int q = 0; q < 9; ++q) s = fmaf(xv[q], ws1[oc * 9 + q], s);
      hr[oc] = f2bf(fmaxf(s, 0.f));
    }
  }
  __syncthreads();
  const uint4* srcv = (const uint4*)h1s;
  uint4* dstv = (uint4*)((char*)h1 + (size_t)img * H1_STRIDE);
  for (int i = t; i < H1_BYTES / 16; i += 256) dstv[i] = srcv[i];
}

// ---- one-off: w2 fp32 [64][32][9] -> wt bf16 [9][64][40] (ic-minor, padded) ----
__global__ __launch_bounds__(256) void k_wt(const float* __restrict__ w2,
    unsigned short* __restrict__ wt) {
  int idx = blockIdx.x * 256 + threadIdx.x;
  if (idx >= WT_ELEMS) return;
  int tap = idx / 2560;
  int r = idx - tap * 2560;
  int oc = r / 40;
  int ic = r - oc * 40;
  unsigned short v = 0;
  if (ic < 32) v = f2bf(w2[oc * 288 + ic * 9 + tap]);
  wt[idx] = v;
}

// ---- one-off: fc1_w [128][9216 (oc*144+sp)] -> fw1t bf16 [128][9216 (sp*64+oc)] ----
__global__ __launch_bounds__(256) void k_fw1t(const float* __restrict__ w,
    unsigned short* __restrict__ wt) {
  int c = blockIdx.x;
  __shared__ float row[9216];
  int t = threadIdx.x;
  const float* src = w + (size_t)c * 9216;
  for (int i = t; i < 9216; i += 256) row[i] = src[i];
  __syncthreads();
  unsigned short* dst = wt + (size_t)c * 9216;
  for (int k = t; k < 9216; k += 256) {
    int sp = k >> 6, oc = k & 63;
    dst[k] = f2bf(row[oc * 144 + sp]);
  }
}

// ---- conv2 + relu + maxpool via MFMA -> pooled bf16 [img][144][64] ----
__global__ __launch_bounds__(256) void k2_mfma(const unsigned short* __restrict__ h1,
    const unsigned short* __restrict__ wt, const float* __restrict__ b2,
    unsigned short* __restrict__ pooled) {
  int img = blockIdx.x;
  __shared__ __align__(16) unsigned short hs[27648];    // 55296 B
  __shared__ __align__(16) unsigned short wsh[23040];   // 46080 B
  int t = threadIdx.x;
  int wv = t >> 6, ln = t & 63;
  const char* gs = (const char*)h1 + (size_t)img * H1_STRIDE + ln * 16;
  char* hsb = (char*)hs;
  #pragma unroll
  for (int c = 0; c < 14; ++c) {          // 54 chunks of 1024 B
    int cc = wv + c * 4;
    if (cc < 54) GLL16(gs + cc * 1024, hsb + cc * 1024);
  }
  const char* gw = (const char*)wt + ln * 16;
  char* wsb = (char*)wsh;
  #pragma unroll
  for (int c = 0; c < 12; ++c) {          // 45 chunks of 1024 B
    int cc = wv + c * 4;
    if (cc < 45) GLL16(gw + cc * 1024, wsb + cc * 1024);
  }
  __syncthreads();

  int col = t & 15;
  int g = (t >> 4) & 3;
  int wave = t >> 6;

  int abase[9];
  #pragma unroll
  for (int m = 0; m < 9; ++m) {
    int mt = wave * 9 + m;
    int pr = mt / 3, tc = mt - pr * 3;
    int y = 2 * pr + (col & 1);
    int xx = 8 * tc + (col >> 1);
    abase[m] = (y * 26 + xx) * 80 + g * 16;
  }
  int bbase = col * 80 + g * 16;

  f32x4 acc[9][4];
  #pragma unroll
  for (int m = 0; m < 9; ++m)
    #pragma unroll
    for (int n = 0; n < 4; ++n)
      acc[m][n] = (f32x4){0.f, 0.f, 0.f, 0.f};

  #pragma unroll
  for (int tap = 0; tap < 9; ++tap) {
    int ky = tap / 3, kx = tap - ky * 3;
    int toff = (ky * 26 + kx) * 80;
    short8 bf[4];
    #pragma unroll
    for (int n = 0; n < 4; ++n)
      bf[n] = *(const short8*)(wsb + bbase + (tap * 64 + n * 16) * 80);
    #pragma unroll
    for (int m = 0; m < 9; ++m) {
      short8 af = *(const short8*)(hsb + abase[m] + toff);
      #pragma unroll
      for (int n = 0; n < 4; ++n)
        acc[m][n] = __builtin_amdgcn_mfma_f32_16x16x32_bf16(af, bf[n], acc[m][n], 0, 0, 0);
    }
  }

  float bias[4];
  #pragma unroll
  for (int n = 0; n < 4; ++n) bias[n] = b2[n * 16 + col];
  unsigned short* pp = pooled + (size_t)img * POOLN;
  #pragma unroll
  for (int m = 0; m < 9; ++m) {
    int mt = wave * 9 + m;
    int pr = mt / 3, tc = mt - pr * 3;
    int sp = pr * 12 + tc * 4 + g;
    #pragma unroll
    for (int n = 0; n < 4; ++n) {
      f32x4 a = acc[m][n];
      float v = fmaxf(fmaxf(a[0], a[1]), fmaxf(a[2], a[3]));
      pp[sp * 64 + n * 16 + col] = f2bf(fmaxf(v + bias[n], 0.f));
    }
  }
}

// ---- fc1 via MFMA, split-K=4: pooled bf16 [nr][9216] @ fw1t bf16 [128][9216]^T
// grid (nrpad/64, 4). Block: BM=64, BN=128, BK=64 double-buffered.
// Wave (wm=wv>>1, wn=wv&1) owns 32x64; per K-step 16 MFMA.
// T2 both-sides XOR swizzle: GLL dest linear, source byte ^((row&7)<<4), read same.
__global__ __launch_bounds__(256) void k3_fc1_mfma(
    const unsigned short* __restrict__ a, const unsigned short* __restrict__ w,
    float* __restrict__ part, int nrpad) {
  __shared__ __align__(16) unsigned short As[2][4096];   // [64][64] bf16 x2
  __shared__ __align__(16) unsigned short Bs[2][8192];   // [128][64] bf16 x2
  int row0 = blockIdx.x * 64;
  int kbase = blockIdx.y * 2304;
  int t = threadIdx.x;
  int wv = t >> 6, l = t & 63;
  int rsub = l >> 3;                          // row within 8-row chunk
  int src_sw = ((l & 7) ^ rsub) << 4;         // pre-swizzled source byte offset

  const char* abase = (const char*)a + (size_t)row0 * 18432;
  const char* bbase = (const char*)w;

  auto stage = [&](int buf, int step) {
    size_t k0b = (size_t)(kbase + step * 64) * 2;
    #pragma unroll
    for (int i = 0; i < 2; ++i) {
      int c = wv * 2 + i;
      GLL16(abase + (size_t)(c * 8 + rsub) * 18432 + k0b + src_sw,
            (char*)As[buf] + c * 1024);
    }
    #pragma unroll
    for (int i = 0; i < 4; ++i) {
      int c = wv * 4 + i;
      GLL16(bbase + (size_t)(c * 8 + rsub) * 18432 + k0b + src_sw,
            (char*)Bs[buf] + c * 1024);
    }
  };

  int wm = wv >> 1, wn = wv & 1;
  int lr = l & 15, g2 = l >> 4;
  int rdxor = (lr & 7) << 4;

  f32x4 acc[2][4];
  #pragma unroll
  for (int mf = 0; mf < 2; ++mf)
    #pragma unroll
    for (int nf = 0; nf < 4; ++nf)
      acc[mf][nf] = (f32x4){0.f, 0.f, 0.f, 0.f};

  stage(0, 0);
  __syncthreads();
  for (int s = 0; s < 36; ++s) {
    int cur = s & 1;
    if (s < 35) stage(cur ^ 1, s + 1);
    const char* Ab = (const char*)As[cur];
    const char* Bb = (const char*)Bs[cur];
    #pragma unroll
    for (int ksub = 0; ksub < 2; ++ksub) {
      int koff = (ksub * 64 + g2 * 16) ^ rdxor;
      short8 af0 = *(const short8*)(Ab + (wm * 32 + lr) * 128 + koff);
      short8 af1 = *(const short8*)(Ab + (wm * 32 + 16 + lr) * 128 + koff);
      short8 bf[4];
      #pragma unroll
      for (int nf = 0; nf < 4; ++nf)
        bf[nf] = *(const short8*)(Bb + (wn * 64 + nf * 16 + lr) * 128 + koff);
      #pragma unroll
      for (int nf = 0; nf < 4; ++nf) {
        acc[0][nf] = __builtin_amdgcn_mfma_f32_16x16x32_bf16(af0, bf[nf], acc[0][nf], 0, 0, 0);
        acc[1][nf] = __builtin_amdgcn_mfma_f32_16x16x32_bf16(af1, bf[nf], acc[1][nf], 0, 0, 0);
      }
    }
    __syncthreads();
  }

  float* pp = part + (size_t)blockIdx.y * nrpad * 128 + (size_t)row0 * 128;
  #pragma unroll
  for (int mf = 0; mf < 2; ++mf)
    #pragma unroll
    for (int nf = 0; nf < 4; ++nf)
      #pragma unroll
      for (int rr = 0; rr < 4; ++rr) {
        int r = wm * 32 + mf * 16 + g2 * 4 + rr;
        int c = wn * 64 + nf * 16 + lr;
        pp[r * 128 + c] = acc[mf][nf][rr];
      }
}

// ---- reduce 4 split-K partials + bias + relu -> f1o fp32 [nr][128] ----
__global__ __launch_bounds__(256) void k_red(const float* __restrict__ part,
    const float* __restrict__ bias, float* __restrict__ f1o, int nr, int nrpad) {
  int i = blockIdx.x * 256 + threadIdx.x;
  if (i >= nr * 128) return;
  size_t stride = (size_t)nrpad * 128;
  float s = part[i] + part[stride + i] + part[2 * stride + i] + part[3 * stride + i];
  f1o[i] = fmaxf(s + bias[i & 127], 0.f);
}

// ---- fc2 ----
__global__ __launch_bounds__(256) void k4_fc2(const float* __restrict__ h,
    const float* __restrict__ w, const float* __restrict__ bias,
    float* __restrict__ out, int nr) {
  int idx = blockIdx.x * 256 + threadIdx.x;
  if (idx >= nr * 10) return;
  int b = idx / 10;
  int j = idx - b * 10;
  const float4* hp = (const float4*)(h + (size_t)b * 128);
  const float4* wp = (const float4*)(w + (size_t)j * 128);
  float s = 0.f;
  #pragma unroll
  for (int q = 0; q < 32; ++q) {
    float4 hv = hp[q];
    float4 wv = wp[q];
    s = fmaf(hv.x, wv.x, s);
    s = fmaf(hv.y, wv.y, s);
    s = fmaf(hv.z, wv.z, s);
    s = fmaf(hv.w, wv.w, s);
  }
  out[idx] = s + bias[j];
}

extern "C" void kernel_launch(void* const* d_in, const int* in_sizes, int n_in,
                              void* d_out, int out_size, void* d_ws, size_t ws_size,
                              hipStream_t stream) {
  const float* x   = (const float*)d_in[0];
  const float* w1  = (const float*)d_in[1];
  const float* b1  = (const float*)d_in[2];
  const float* w2  = (const float*)d_in[3];
  const float* b2  = (const float*)d_in[4];
  const float* fw1 = (const float*)d_in[5];
  const float* fb1 = (const float*)d_in[6];
  const float* fw2 = (const float*)d_in[7];
  const float* fb2 = (const float*)d_in[8];
  float* out = (float*)d_out;

  const int B = in_sizes[0] / 784;

  unsigned short* wt = (unsigned short*)d_ws;                       // 46080 B
  unsigned short* fw1t = (unsigned short*)((char*)d_ws + WT_BYTES); // 2359296 B
  const size_t carve = WT_BYTES + (size_t)POOLN * 128 / 64 * 2 * 64;  // 46080 + 2359296
  char* base = (char*)d_ws + carve;
  size_t avail = (ws_size > carve) ? ws_size - carve : 0;
  // per image: h1 55296 + pooled(bf16) 18432 + f1o 512 + partials 4*512
  const size_t per_img = H1_STRIDE + (size_t)POOLN * 2 + 512 + 2048;
  int Bc = (int)(avail / per_img);
  if (Bc > B) Bc = B;
  Bc &= ~63;
  if (Bc < 64) Bc = 64;

  unsigned short* h1 = (unsigned short*)base;
  unsigned short* pooled = (unsigned short*)(base + (size_t)Bc * H1_STRIDE);
  float* f1o = (float*)(base + (size_t)Bc * (H1_STRIDE + POOLN * 2));
  float* part = (float*)(base + (size_t)Bc * (H1_STRIDE + POOLN * 2 + 512));

  k_wt<<<(WT_ELEMS + 255) / 256, 256, 0, stream>>>(w2, wt);
  k_fw1t<<<128, 256, 0, stream>>>(fw1, fw1t);

  for (int i0 = 0; i0 < B; i0 += Bc) {
    int nr = (B - i0 < Bc) ? (B - i0) : Bc;
    int mtiles = (nr + 63) / 64;
    int nrpad = mtiles * 64;
    k1_conv1<<<nr, 256, 0, stream>>>(x + (size_t)i0 * 784, w1, b1, h1);
    k2_mfma<<<nr, 256, 0, stream>>>(h1, wt, b2, pooled);
    k3_fc1_mfma<<<dim3(mtiles, 4), 256, 0, stream>>>(pooled, fw1t, part, nrpad);
    k_red<<<(nr * 128 + 255) / 256, 256, 0, stream>>>(part, fb1, f1o, nr, nrpad);
    k4_fc2<<<(nr * 10 + 255) / 256, 256, 0, stream>>>(f1o, fw2, fb2,
                                                      out + (size_t)i0 * 10, nr);
  }
}

// Round 4
// 156.719 us; speedup vs baseline: 47.9673x; 2.1548x over previous
//
#include <hip/hip_runtime.h>

using short8 = __attribute__((ext_vector_type(8))) short;
using f32x4  = __attribute__((ext_vector_type(4))) float;

#define POOLN     9216       // 144*64 elements (bf16) per image
#define FC1N      128
#define WT2_ELEMS 18432      // 36*64*8
#define WT2_BYTES 36864

#define GLL16(gp, lp) __builtin_amdgcn_global_load_lds( \
    (const __attribute__((address_space(1))) void*)(gp), \
    (__attribute__((address_space(3))) void*)(lp), 16, 0, 0)

static __device__ __forceinline__ unsigned short f2bf(float f) {
  unsigned int u = __builtin_bit_cast(unsigned int, f);
  unsigned int r = (u + 0x7FFFu + ((u >> 16) & 1u)) >> 16;
  return (unsigned short)r;
}

// ---- one-off: w2 fp32 [64][32][9] -> wt2 bf16 fragment order [(tap*4+n)][lane][8]
// lane l holds oc = n*16 + (l&15), ic = (l>>4)*8 + j  (exact MFMA B-frag layout)
__global__ __launch_bounds__(256) void k_wt2(const float* __restrict__ w2,
    unsigned short* __restrict__ wt2) {
  int idx = blockIdx.x * 256 + threadIdx.x;
  if (idx >= WT2_ELEMS) return;
  int j = idx & 7;
  int l = (idx >> 3) & 63;
  int tn = idx >> 9;            // 0..35
  int tap = tn >> 2, n = tn & 3;
  int oc = n * 16 + (l & 15);
  int ic = (l >> 4) * 8 + j;
  wt2[idx] = f2bf(w2[oc * 288 + ic * 9 + tap]);
}

// ---- one-off: fc1_w [128][9216 (oc*144+sp)] -> fw1t bf16 [128][9216 (sp*64+oc)] ----
__global__ __launch_bounds__(256) void k_fw1t(const float* __restrict__ w,
    unsigned short* __restrict__ wt) {
  int c = blockIdx.x;
  __shared__ float row[9216];
  int t = threadIdx.x;
  const float* src = w + (size_t)c * 9216;
  for (int i = t; i < 9216; i += 256) row[i] = src[i];
  __syncthreads();
  unsigned short* dst = wt + (size_t)c * 9216;
  for (int k = t; k < 9216; k += 256) {
    int sp = k >> 6, oc = k & 63;
    dst[k] = f2bf(row[oc * 144 + sp]);
  }
}

// ---- fused conv1+relu+conv2+relu+maxpool -> pooled bf16 [img][144][64] ----
// One block per image, 4 waves, 2 blocks/CU (58KB LDS).
// conv1: wave wv owns oc 8wv..8wv+7 (weights wave-uniform); lane<52: row ln>>1,
//        col span (ln&1)*13, 3x3 sliding window, packed ds_write_b128 into h1s.
// conv2: A-frags from h1s (HWC-40 bf16), B-frags 16B/lane coalesced global loads
//        from wt2 (L2-hot), 9 taps x 9 m-tiles x 4 n per wave.
__global__ __launch_bounds__(256, 2) void kc_fused(const float* __restrict__ x,
    const float* __restrict__ w1, const float* __restrict__ b1,
    const unsigned short* __restrict__ wt2, const float* __restrict__ b2,
    unsigned short* __restrict__ pooled) {
  int img = blockIdx.x;
  __shared__ float xs[784];
  __shared__ __align__(16) unsigned short h1s[27040];   // [676][40] bf16, 54080 B
  int t = threadIdx.x;
  int wv = t >> 6, ln = t & 63;

  const float* xp = x + (size_t)img * 784;
  for (int i = t; i < 784; i += 256) xs[i] = xp[i];

  // conv1 weights, wave-uniform (force SGPR via readfirstlane)
  int wvu = __builtin_amdgcn_readfirstlane(wv);
  float wr[8][9], br[8];
  #pragma unroll
  for (int o = 0; o < 8; ++o) {
    br[o] = b1[wvu * 8 + o];
    #pragma unroll
    for (int q = 0; q < 9; ++q) wr[o][q] = w1[(wvu * 8 + o) * 9 + q];
  }
  __syncthreads();

  if (ln < 52) {
    int oy = ln >> 1, x0 = (ln & 1) * 13;
    float win[3][3];
    #pragma unroll
    for (int r = 0; r < 3; ++r) {
      win[r][1] = xs[(oy + r) * 28 + x0];
      win[r][2] = xs[(oy + r) * 28 + x0 + 1];
    }
    for (int px = 0; px < 13; ++px) {
      #pragma unroll
      for (int r = 0; r < 3; ++r) {
        win[r][0] = win[r][1];
        win[r][1] = win[r][2];
        win[r][2] = xs[(oy + r) * 28 + x0 + px + 2];
      }
      unsigned int packed[4];
      #pragma unroll
      for (int o = 0; o < 8; o += 2) {
        float s0 = br[o], s1 = br[o + 1];
        #pragma unroll
        for (int r = 0; r < 3; ++r)
          #pragma unroll
          for (int c = 0; c < 3; ++c) {
            s0 = fmaf(win[r][c], wr[o][r * 3 + c], s0);
            s1 = fmaf(win[r][c], wr[o + 1][r * 3 + c], s1);
          }
        unsigned int lo = f2bf(fmaxf(s0, 0.f));
        unsigned int hi = f2bf(fmaxf(s1, 0.f));
        packed[o >> 1] = lo | (hi << 16);
      }
      int pos = oy * 26 + x0 + px;
      uint4 v = {packed[0], packed[1], packed[2], packed[3]};
      *(uint4*)&h1s[pos * 40 + wv * 8] = v;
    }
  }
  __syncthreads();

  // ---- conv2 + pool ----
  int col = ln & 15;
  int g = (ln >> 4) & 3;

  int abase[9];
  #pragma unroll
  for (int m = 0; m < 9; ++m) {
    int mt = wv * 9 + m;
    int pr = mt / 3, tc = mt - pr * 3;
    int y = 2 * pr + (col & 1);
    int xx = 8 * tc + (col >> 1);
    abase[m] = (y * 26 + xx) * 80 + g * 16;
  }

  f32x4 acc[9][4];
  #pragma unroll
  for (int m = 0; m < 9; ++m)
    #pragma unroll
    for (int n = 0; n < 4; ++n)
      acc[m][n] = (f32x4){0.f, 0.f, 0.f, 0.f};

  const char* hsb = (const char*)h1s;
  #pragma unroll
  for (int tap = 0; tap < 9; ++tap) {
    int ky = tap / 3, kx = tap - ky * 3;
    int toff = (ky * 26 + kx) * 80;
    short8 bf[4];
    #pragma unroll
    for (int n = 0; n < 4; ++n)
      bf[n] = *(const short8*)(wt2 + ((size_t)(tap * 4 + n) * 64 + ln) * 8);
    #pragma unroll
    for (int m = 0; m < 9; ++m) {
      short8 af = *(const short8*)(hsb + abase[m] + toff);
      #pragma unroll
      for (int n = 0; n < 4; ++n)
        acc[m][n] = __builtin_amdgcn_mfma_f32_16x16x32_bf16(af, bf[n], acc[m][n], 0, 0, 0);
    }
  }

  float bias[4];
  #pragma unroll
  for (int n = 0; n < 4; ++n) bias[n] = b2[n * 16 + col];
  unsigned short* pp = pooled + (size_t)img * POOLN;
  #pragma unroll
  for (int m = 0; m < 9; ++m) {
    int mt = wv * 9 + m;
    int pr = mt / 3, tc = mt - pr * 3;
    int sp = pr * 12 + tc * 4 + g;
    #pragma unroll
    for (int n = 0; n < 4; ++n) {
      f32x4 a = acc[m][n];
      float v = fmaxf(fmaxf(a[0], a[1]), fmaxf(a[2], a[3]));
      pp[sp * 64 + n * 16 + col] = f2bf(fmaxf(v + bias[n], 0.f));
    }
  }
}

// ---- fc1 via MFMA, split-K=4: pooled bf16 [nr][9216] @ fw1t bf16 [128][9216]^T
__global__ __launch_bounds__(256) void k3_fc1_mfma(
    const unsigned short* __restrict__ a, const unsigned short* __restrict__ w,
    float* __restrict__ part, int nrpad) {
  __shared__ __align__(16) unsigned short As[2][4096];   // [64][64] bf16 x2
  __shared__ __align__(16) unsigned short Bs[2][8192];   // [128][64] bf16 x2
  int row0 = blockIdx.x * 64;
  int kbase = blockIdx.y * 2304;
  int t = threadIdx.x;
  int wv = t >> 6, l = t & 63;
  int rsub = l >> 3;
  int src_sw = ((l & 7) ^ rsub) << 4;

  const char* abase = (const char*)a + (size_t)row0 * 18432;
  const char* bbase = (const char*)w;

  auto stage = [&](int buf, int step) {
    size_t k0b = (size_t)(kbase + step * 64) * 2;
    #pragma unroll
    for (int i = 0; i < 2; ++i) {
      int c = wv * 2 + i;
      GLL16(abase + (size_t)(c * 8 + rsub) * 18432 + k0b + src_sw,
            (char*)As[buf] + c * 1024);
    }
    #pragma unroll
    for (int i = 0; i < 4; ++i) {
      int c = wv * 4 + i;
      GLL16(bbase + (size_t)(c * 8 + rsub) * 18432 + k0b + src_sw,
            (char*)Bs[buf] + c * 1024);
    }
  };

  int wm = wv >> 1, wn = wv & 1;
  int lr = l & 15, g2 = l >> 4;
  int rdxor = (lr & 7) << 4;

  f32x4 acc[2][4];
  #pragma unroll
  for (int mf = 0; mf < 2; ++mf)
    #pragma unroll
    for (int nf = 0; nf < 4; ++nf)
      acc[mf][nf] = (f32x4){0.f, 0.f, 0.f, 0.f};

  stage(0, 0);
  __syncthreads();
  for (int s = 0; s < 36; ++s) {
    int cur = s & 1;
    if (s < 35) stage(cur ^ 1, s + 1);
    const char* Ab = (const char*)As[cur];
    const char* Bb = (const char*)Bs[cur];
    #pragma unroll
    for (int ksub = 0; ksub < 2; ++ksub) {
      int koff = (ksub * 64 + g2 * 16) ^ rdxor;
      short8 af0 = *(const short8*)(Ab + (wm * 32 + lr) * 128 + koff);
      short8 af1 = *(const short8*)(Ab + (wm * 32 + 16 + lr) * 128 + koff);
      short8 bf[4];
      #pragma unroll
      for (int nf = 0; nf < 4; ++nf)
        bf[nf] = *(const short8*)(Bb + (wn * 64 + nf * 16 + lr) * 128 + koff);
      #pragma unroll
      for (int nf = 0; nf < 4; ++nf) {
        acc[0][nf] = __builtin_amdgcn_mfma_f32_16x16x32_bf16(af0, bf[nf], acc[0][nf], 0, 0, 0);
        acc[1][nf] = __builtin_amdgcn_mfma_f32_16x16x32_bf16(af1, bf[nf], acc[1][nf], 0, 0, 0);
      }
    }
    __syncthreads();
  }

  float* pp = part + (size_t)blockIdx.y * nrpad * 128 + (size_t)row0 * 128;
  #pragma unroll
  for (int mf = 0; mf < 2; ++mf)
    #pragma unroll
    for (int nf = 0; nf < 4; ++nf)
      #pragma unroll
      for (int rr = 0; rr < 4; ++rr) {
        int r = wm * 32 + mf * 16 + g2 * 4 + rr;
        int c = wn * 64 + nf * 16 + lr;
        pp[r * 128 + c] = acc[mf][nf][rr];
      }
}

// ---- reduce 4 split-K partials + bias + relu -> f1o fp32 [nr][128] ----
__global__ __launch_bounds__(256) void k_red(const float* __restrict__ part,
    const float* __restrict__ bias, float* __restrict__ f1o, int nr, int nrpad) {
  int i = blockIdx.x * 256 + threadIdx.x;
  if (i >= nr * 128) return;
  size_t stride = (size_t)nrpad * 128;
  float s = part[i] + part[stride + i] + part[2 * stride + i] + part[3 * stride + i];
  f1o[i] = fmaxf(s + bias[i & 127], 0.f);
}

// ---- fc2 ----
__global__ __launch_bounds__(256) void k4_fc2(const float* __restrict__ h,
    const float* __restrict__ w, const float* __restrict__ bias,
    float* __restrict__ out, int nr) {
  int idx = blockIdx.x * 256 + threadIdx.x;
  if (idx >= nr * 10) return;
  int b = idx / 10;
  int j = idx - b * 10;
  const float4* hp = (const float4*)(h + (size_t)b * 128);
  const float4* wp = (const float4*)(w + (size_t)j * 128);
  float s = 0.f;
  #pragma unroll
  for (int q = 0; q < 32; ++q) {
    float4 hv = hp[q];
    float4 wv = wp[q];
    s = fmaf(hv.x, wv.x, s);
    s = fmaf(hv.y, wv.y, s);
    s = fmaf(hv.z, wv.z, s);
    s = fmaf(hv.w, wv.w, s);
  }
  out[idx] = s + bias[j];
}

extern "C" void kernel_launch(void* const* d_in, const int* in_sizes, int n_in,
                              void* d_out, int out_size, void* d_ws, size_t ws_size,
                              hipStream_t stream) {
  const float* x   = (const float*)d_in[0];
  const float* w1  = (const float*)d_in[1];
  const float* b1  = (const float*)d_in[2];
  const float* w2  = (const float*)d_in[3];
  const float* b2  = (const float*)d_in[4];
  const float* fw1 = (const float*)d_in[5];
  const float* fb1 = (const float*)d_in[6];
  const float* fw2 = (const float*)d_in[7];
  const float* fb2 = (const float*)d_in[8];
  float* out = (float*)d_out;

  const int B = in_sizes[0] / 784;

  unsigned short* wt2 = (unsigned short*)d_ws;                        // 36864 B
  unsigned short* fw1t = (unsigned short*)((char*)d_ws + WT2_BYTES);  // 2359296 B
  const size_t carve = WT2_BYTES + (size_t)9216 * 128 * 2;
  char* base = (char*)d_ws + carve;
  size_t avail = (ws_size > carve) ? ws_size - carve : 0;
  // per image: pooled(bf16) 18432 + f1o 512 + partials 4*512
  const size_t per_img = (size_t)POOLN * 2 + 512 + 2048;
  int Bc = (int)(avail / per_img);
  if (Bc > B) Bc = B;
  Bc &= ~63;
  if (Bc < 64) Bc = 64;

  unsigned short* pooled = (unsigned short*)base;
  float* f1o = (float*)(base + (size_t)Bc * (POOLN * 2));
  float* part = (float*)(base + (size_t)Bc * (POOLN * 2 + 512));

  k_wt2<<<(WT2_ELEMS + 255) / 256, 256, 0, stream>>>(w2, wt2);
  k_fw1t<<<128, 256, 0, stream>>>(fw1, fw1t);

  for (int i0 = 0; i0 < B; i0 += Bc) {
    int nr = (B - i0 < Bc) ? (B - i0) : Bc;
    int mtiles = (nr + 63) / 64;
    int nrpad = mtiles * 64;
    kc_fused<<<nr, 256, 0, stream>>>(x + (size_t)i0 * 784, w1, b1, wt2, b2, pooled);
    k3_fc1_mfma<<<dim3(mtiles, 4), 256, 0, stream>>>(pooled, fw1t, part, nrpad);
    k_red<<<(nr * 128 + 255) / 256, 256, 0, stream>>>(part, fb1, f1o, nr, nrpad);
    k4_fc2<<<(nr * 10 + 255) / 256, 256, 0, stream>>>(f1o, fw2, fb2,
                                                      out + (size_t)i0 * 10, nr);
  }
}